// Round 9
// baseline (1098.489 us; speedup 1.0000x reference)
//
#include <hip/hip_runtime.h>

typedef _Float16 f16;
typedef _Float16 f16x2 __attribute__((ext_vector_type(2)));
typedef _Float16 f16x4 __attribute__((ext_vector_type(4)));
typedef _Float16 f16x8 __attribute__((ext_vector_type(8)));
typedef float    f32x4 __attribute__((ext_vector_type(4)));

__device__ __forceinline__ int sdot4(int a, int b, int c) {
#if __has_builtin(__builtin_amdgcn_sdot4)
  return __builtin_amdgcn_sdot4(a, b, c, false);
#else
#pragma unroll
  for (int i = 0; i < 4; ++i)
    c += ((a << (24 - 8 * i)) >> 24) * ((b << (24 - 8 * i)) >> 24);
  return c;
#endif
}

// ---------------- small helper kernels ----------------

__global__ void cvt_f32_to_f16(const float* __restrict__ in, f16* __restrict__ out, int n) {
  int i = (blockIdx.x * blockDim.x + threadIdx.x) * 4;
  if (i + 3 < n) {
    float4 v = *(const float4*)(in + i);
    f16x4 h; h[0] = (f16)v.x; h[1] = (f16)v.y; h[2] = (f16)v.z; h[3] = (f16)v.w;
    *(f16x4*)(out + i) = h;
  }
}

__global__ void bias_comb_kernel(const float* __restrict__ a, const float* __restrict__ b,
                                 float* __restrict__ o, int n) {
  int i = blockIdx.x * blockDim.x + threadIdx.x;
  if (i < n) o[i] = a[i] + b[i];
}

__global__ void zero_u32_kernel(unsigned* p) { *p = 0u; }

// abs-max of W into *out (uint-ordered float bits; all values >= 0)
__global__ void wabsmax_kernel(const float* __restrict__ in, int n, unsigned* out) {
  float m = 0.f;
  for (int i = blockIdx.x * blockDim.x + threadIdx.x; i < n; i += gridDim.x * blockDim.x)
    m = fmaxf(m, fabsf(in[i]));
#pragma unroll
  for (int off = 32; off >= 1; off >>= 1)
    m = fmaxf(m, __shfl_xor(m, off));
  if ((threadIdx.x & 63) == 0) atomicMax(out, __float_as_uint(m));
}

// quantize W to i8 with scale s = wmax/127
__global__ void quant_w_kernel(const float* __restrict__ W, signed char* __restrict__ out,
                               const unsigned* __restrict__ wmax, int n) {
  float mx = __uint_as_float(*wmax);
  float inv = mx > 0.f ? 127.f / mx : 0.f;
  int i = (blockIdx.x * blockDim.x + threadIdx.x) * 4;
  if (i + 3 < n) {
    float4 v = *(const float4*)(W + i);
    int q0 = (int)__builtin_rintf(v.x * inv);
    int q1 = (int)__builtin_rintf(v.y * inv);
    int q2 = (int)__builtin_rintf(v.z * inv);
    int q3 = (int)__builtin_rintf(v.w * inv);
    unsigned p = (unsigned)(q0 & 255) | ((unsigned)(q1 & 255) << 8) |
                 ((unsigned)(q2 & 255) << 16) | ((unsigned)(q3 & 255) << 24);
    *(unsigned*)(out + i) = p;
  }
}

// ---------------- GEMM: C[M,N] = A[M,K] * B[N,K]^T + bias[N] ----------------

#define BM 128
#define BN 128
#define BKT 32
#define LDK 40  // padded leading dim (f16 elems) to dodge bank conflicts

template <bool A_IS_F32>
__global__ __launch_bounds__(256, 2) void gemm_f16_kernel(
    const void* __restrict__ Aptr,    // [M][K]
    const f16* __restrict__ B,        // [N][K]
    const float* __restrict__ bias,   // [N]
    float* __restrict__ C,            // [M][N]
    int M, int N, int K) {
  __shared__ f16 As[BM][LDK];
  __shared__ f16 Bs[BN][LDK];

  const int tid = threadIdx.x;
  const int bm = blockIdx.y, bn = blockIdx.x;
  const int wave = tid >> 6, lane = tid & 63;
  const int wm = wave >> 1, wn = wave & 1;

  f32x4 acc[4][4] = {};

  for (int k0 = 0; k0 < K; k0 += BKT) {
#pragma unroll
    for (int it = 0; it < 2; ++it) {
      int idx = tid + it * 256;          // 0..511
      int row = idx >> 2;                // 0..127
      int kc  = (idx & 3) << 3;          // 0,8,16,24
      if (A_IS_F32) {
        const float* Af = (const float*)Aptr + (size_t)(bm * BM + row) * K + k0 + kc;
        float4 v0 = *(const float4*)Af;
        float4 v1 = *(const float4*)(Af + 4);
        f16x8 h;
        h[0] = (f16)v0.x; h[1] = (f16)v0.y; h[2] = (f16)v0.z; h[3] = (f16)v0.w;
        h[4] = (f16)v1.x; h[5] = (f16)v1.y; h[6] = (f16)v1.z; h[7] = (f16)v1.w;
        *(f16x8*)&As[row][kc] = h;
      } else {
        const f16* Ah = (const f16*)Aptr + (size_t)(bm * BM + row) * K + k0 + kc;
        *(f16x8*)&As[row][kc] = *(const f16x8*)Ah;
      }
      const f16* Bh = B + (size_t)(bn * BN + row) * K + k0 + kc;
      *(f16x8*)&Bs[row][kc] = *(const f16x8*)Bh;
    }
    __syncthreads();

    const int fr = lane & 15;
    const int fk = (lane >> 4) << 3;  // 0,8,16,24
    f16x8 af[4], bf[4];
#pragma unroll
    for (int i = 0; i < 4; ++i) af[i] = *(const f16x8*)&As[wm * 64 + i * 16 + fr][fk];
#pragma unroll
    for (int j = 0; j < 4; ++j) bf[j] = *(const f16x8*)&Bs[wn * 64 + j * 16 + fr][fk];
#pragma unroll
    for (int i = 0; i < 4; ++i)
#pragma unroll
      for (int j = 0; j < 4; ++j)
        acc[i][j] = __builtin_amdgcn_mfma_f32_16x16x32_f16(af[i], bf[j], acc[i][j], 0, 0, 0);
    __syncthreads();
  }

  const int fr = lane & 15;
  const int fq = lane >> 4;
#pragma unroll
  for (int i = 0; i < 4; ++i)
#pragma unroll
    for (int j = 0; j < 4; ++j)
#pragma unroll
      for (int r = 0; r < 4; ++r) {
        int row = bm * BM + wm * 64 + i * 16 + fq * 4 + r;
        int col = bn * BN + wn * 64 + j * 16 + fr;
        C[(size_t)row * N + col] = acc[i][j][r] + bias[col];
      }
}

// ---------------- recurrent scan (int8, split-k, NAMED-scalar W) ----------------
// Rounds 1-8 post-mortem: W arrays (>SROA threshold) silently live in scratch
// and are re-loaded from L2 every step. Fix: 64 NAMED int scalars per thread
// (born SSA, no SROA needed) + asm pin (no load-remat). Split-k over 1024
// threads: thread (j = tid&511, kh = tid>>9) owns dwords [kh*64, kh*64+64) of
// W row j. waves_per_eu(4,4) pins the budget at 128 VGPRs (16 waves/CU = this
// block). h i8 in LDS; 16 uniform ds_read_b128 broadcasts per thread per step;
// integer partial combine via LDS (exact), 2 barriers/step.

#define ST 1024

#define STEP_CHUNK(c, wa, wb, wcc, wd) \
  { int4 hv = bcp[c];                  \
    a0 = sdot4(wa, hv.x, a0);          \
    a1 = sdot4(wb, hv.y, a1);          \
    a2 = sdot4(wcc, hv.z, a2);         \
    a3 = sdot4(wd, hv.w, a3); }

__global__ __attribute__((amdgpu_flat_work_group_size(ST, ST),
                          amdgpu_waves_per_eu(4, 4)))
void rnn_scan_kernel(
    const signed char* __restrict__ Whq,  // [512][512] i8
    const unsigned* __restrict__ wmax,    // scale source
    const float* __restrict__ h0,         // [B][512] f32
    const float* __restrict__ xp,         // [B][T][512] f32 (pre-act incl. biases)
    f16* __restrict__ hs,                 // [B][T][512] f16 (out, for y-GEMM)
    float* __restrict__ hn,               // [B][512] f32 (out)
    int T) {
  __shared__ __align__(16) signed char hbuf[2][512];   // 1 KB
  __shared__ int ipart[512];                           // 2 KB

  const int tid = threadIdx.x;
  const int j   = tid & 511;
  const int kh  = tid >> 9;          // wave-uniform
  const int b   = blockIdx.x;

  // combined dequant scale: value = acc_int * (wmax/127) * (1/127)
  const float qs = __uint_as_float(*wmax) * (1.0f / 16129.0f);

  // W row j, k-half kh: 64 dwords of packed i8 -> 64 NAMED scalars (SSA)
  const int* wrow = (const int*)(Whq + (size_t)j * 512) + kh * 64;
  int w0 =wrow[0],  w1 =wrow[1],  w2 =wrow[2],  w3 =wrow[3],
      w4 =wrow[4],  w5 =wrow[5],  w6 =wrow[6],  w7 =wrow[7];
  int w8 =wrow[8],  w9 =wrow[9],  w10=wrow[10], w11=wrow[11],
      w12=wrow[12], w13=wrow[13], w14=wrow[14], w15=wrow[15];
  int w16=wrow[16], w17=wrow[17], w18=wrow[18], w19=wrow[19],
      w20=wrow[20], w21=wrow[21], w22=wrow[22], w23=wrow[23];
  int w24=wrow[24], w25=wrow[25], w26=wrow[26], w27=wrow[27],
      w28=wrow[28], w29=wrow[29], w30=wrow[30], w31=wrow[31];
  int w32=wrow[32], w33=wrow[33], w34=wrow[34], w35=wrow[35],
      w36=wrow[36], w37=wrow[37], w38=wrow[38], w39=wrow[39];
  int w40=wrow[40], w41=wrow[41], w42=wrow[42], w43=wrow[43],
      w44=wrow[44], w45=wrow[45], w46=wrow[46], w47=wrow[47];
  int w48=wrow[48], w49=wrow[49], w50=wrow[50], w51=wrow[51],
      w52=wrow[52], w53=wrow[53], w54=wrow[54], w55=wrow[55];
  int w56=wrow[56], w57=wrow[57], w58=wrow[58], w59=wrow[59],
      w60=wrow[60], w61=wrow[61], w62=wrow[62], w63=wrow[63];
  // pin: asm defs cannot be rematerialized as loads
  asm volatile("" : "+v"(w0),"+v"(w1),"+v"(w2),"+v"(w3),"+v"(w4),"+v"(w5),"+v"(w6),"+v"(w7));
  asm volatile("" : "+v"(w8),"+v"(w9),"+v"(w10),"+v"(w11),"+v"(w12),"+v"(w13),"+v"(w14),"+v"(w15));
  asm volatile("" : "+v"(w16),"+v"(w17),"+v"(w18),"+v"(w19),"+v"(w20),"+v"(w21),"+v"(w22),"+v"(w23));
  asm volatile("" : "+v"(w24),"+v"(w25),"+v"(w26),"+v"(w27),"+v"(w28),"+v"(w29),"+v"(w30),"+v"(w31));
  asm volatile("" : "+v"(w32),"+v"(w33),"+v"(w34),"+v"(w35),"+v"(w36),"+v"(w37),"+v"(w38),"+v"(w39));
  asm volatile("" : "+v"(w40),"+v"(w41),"+v"(w42),"+v"(w43),"+v"(w44),"+v"(w45),"+v"(w46),"+v"(w47));
  asm volatile("" : "+v"(w48),"+v"(w49),"+v"(w50),"+v"(w51),"+v"(w52),"+v"(w53),"+v"(w54),"+v"(w55));
  asm volatile("" : "+v"(w56),"+v"(w57),"+v"(w58),"+v"(w59),"+v"(w60),"+v"(w61),"+v"(w62),"+v"(w63));

  if (kh == 0) {
    float hv = h0[(size_t)b * 512 + j];
    hv = fminf(1.f, fmaxf(-1.f, hv));
    hbuf[0][j] = (signed char)(int)__builtin_rintf(127.f * hv);
  }
  __syncthreads();

  const float* xpb = xp + (size_t)b * T * 512 + j;
  f16* hsb = hs + (size_t)b * T * 512 + j;

  int cur = 0;
  float hlast = 0.f;
  float xv = (kh == 0) ? xpb[0] : 0.f;
  for (int t = 0; t < T; ++t) {
    float xn = xv;
    if (kh == 0) {                      // wave-uniform branch
      int tn = t + 1 < T ? t + 1 : t;
      xn = xpb[(size_t)tn * 512];       // prefetch next step's xp
    }

    const int4* bcp = (const int4*)hbuf[cur] + kh * 16;
    int a0 = 0, a1 = 0, a2 = 0, a3 = 0;
    STEP_CHUNK( 0, w0,  w1,  w2,  w3 )
    STEP_CHUNK( 1, w4,  w5,  w6,  w7 )
    STEP_CHUNK( 2, w8,  w9,  w10, w11)
    STEP_CHUNK( 3, w12, w13, w14, w15)
    STEP_CHUNK( 4, w16, w17, w18, w19)
    STEP_CHUNK( 5, w20, w21, w22, w23)
    STEP_CHUNK( 6, w24, w25, w26, w27)
    STEP_CHUNK( 7, w28, w29, w30, w31)
    STEP_CHUNK( 8, w32, w33, w34, w35)
    STEP_CHUNK( 9, w36, w37, w38, w39)
    STEP_CHUNK(10, w40, w41, w42, w43)
    STEP_CHUNK(11, w44, w45, w46, w47)
    STEP_CHUNK(12, w48, w49, w50, w51)
    STEP_CHUNK(13, w52, w53, w54, w55)
    STEP_CHUNK(14, w56, w57, w58, w59)
    STEP_CHUNK(15, w60, w61, w62, w63)
    int ai = (a0 + a1) + (a2 + a3);

    if (kh == 1) ipart[j] = ai;
    __syncthreads();

    if (kh == 0) {
      float acc = (float)(ai + ipart[j]) * qs + xv;
      // tanh(x) = 1 - 2/(exp(2x)+1); branch-free
      float e = __expf(2.0f * acc);
      float hnew = 1.0f - 2.0f * __builtin_amdgcn_rcpf(e + 1.0f);
      hlast = hnew;
      hsb[(size_t)t * 512] = (f16)hnew;
      hbuf[cur ^ 1][j] = (signed char)(int)__builtin_rintf(127.f * hnew);
    }
    __syncthreads();
    cur ^= 1;
    xv = xn;
  }
  if (kh == 0) hn[(size_t)b * 512 + j] = hlast;
}

// ---------------- launch ----------------

extern "C" void kernel_launch(void* const* d_in, const int* in_sizes, int n_in,
                              void* d_out, int out_size, void* d_ws, size_t ws_size,
                              hipStream_t stream) {
  const float* x    = (const float*)d_in[0];
  const float* h0   = (const float*)d_in[1];
  const float* W_xh = (const float*)d_in[2];
  const float* b_xh = (const float*)d_in[3];
  const float* W_hh = (const float*)d_in[4];
  const float* b_hh = (const float*)d_in[5];
  const float* W_hy = (const float*)d_in[6];
  const float* b_hy = (const float*)d_in[7];

  const int H = 512;
  const int B = in_sizes[1] / H;            // 64
  const int T = in_sizes[0] / (B * H);      // 1024
  const int M = B * T;                      // 65536

  float* out = (float*)d_out;               // y [M][512] then h_n [B][512]
  float* xpb = out;                         // reuse y region as xp scratch
  float* hn  = out + (size_t)M * H;

  char* w = (char*)d_ws;
  f16*         hsb    = (f16*)w;                              // M*H*2 bytes
  f16*         Wxh_h  = (f16*)(w + (size_t)M * H * 2);        // H*H f16
  f16*         Why_h  = Wxh_h + H * H;                        // H*H f16
  signed char* Whq    = (signed char*)(Why_h + H * H);        // H*H i8
  float*       biasc  = (float*)(Whq + H * H);                // H f32
  unsigned*    wmax   = (unsigned*)(biasc + H);               // 1 u32

  const int WN = H * H;  // 262144
  cvt_f32_to_f16<<<WN / 1024, 256, 0, stream>>>(W_xh, Wxh_h, WN);
  cvt_f32_to_f16<<<WN / 1024, 256, 0, stream>>>(W_hy, Why_h, WN);
  bias_comb_kernel<<<2, 256, 0, stream>>>(b_xh, b_hh, biasc, H);

  // quantize W_hh to i8 with measured absmax scale
  zero_u32_kernel<<<1, 1, 0, stream>>>(wmax);
  wabsmax_kernel<<<64, 256, 0, stream>>>(W_hh, WN, wmax);
  quant_w_kernel<<<WN / 1024, 256, 0, stream>>>(W_hh, Whq, wmax, WN);

  // xp = x @ W_xh^T + (b_xh + b_hh)   (written into d_out)
  gemm_f16_kernel<true><<<dim3(H / BN, M / BM), 256, 0, stream>>>(
      x, Wxh_h, biasc, xpb, M, H, H);

  // sequential scan; writes hs (f16, ws) and h_n (f32, d_out tail)
  rnn_scan_kernel<<<B, ST, 0, stream>>>(Whq, wmax, h0, xpb, hsb, hn, T);

  // y = hs @ W_hy^T + b_hy   (overwrites xp region of d_out)
  gemm_f16_kernel<false><<<dim3(H / BN, M / BM), 256, 0, stream>>>(
      hsb, Why_h, b_hy, out, M, H, H);
}

// Round 10
// 951.510 us; speedup vs baseline: 1.1545x; 1.1545x over previous
//
#include <hip/hip_runtime.h>

typedef _Float16 f16;
typedef _Float16 f16x2 __attribute__((ext_vector_type(2)));
typedef _Float16 f16x4 __attribute__((ext_vector_type(4)));
typedef _Float16 f16x8 __attribute__((ext_vector_type(8)));
typedef float    f32x4 __attribute__((ext_vector_type(4)));

__device__ __forceinline__ int sdot4(int a, int b, int c) {
#if __has_builtin(__builtin_amdgcn_sdot4)
  return __builtin_amdgcn_sdot4(a, b, c, false);
#else
#pragma unroll
  for (int i = 0; i < 4; ++i)
    c += ((a << (24 - 8 * i)) >> 24) * ((b << (24 - 8 * i)) >> 24);
  return c;
#endif
}

// ---------------- small helper kernels ----------------

__global__ void cvt_f32_to_f16(const float* __restrict__ in, f16* __restrict__ out, int n) {
  int i = (blockIdx.x * blockDim.x + threadIdx.x) * 4;
  if (i + 3 < n) {
    float4 v = *(const float4*)(in + i);
    f16x4 h; h[0] = (f16)v.x; h[1] = (f16)v.y; h[2] = (f16)v.z; h[3] = (f16)v.w;
    *(f16x4*)(out + i) = h;
  }
}

__global__ void bias_comb_kernel(const float* __restrict__ a, const float* __restrict__ b,
                                 float* __restrict__ o, int n) {
  int i = blockIdx.x * blockDim.x + threadIdx.x;
  if (i < n) o[i] = a[i] + b[i];
}

__global__ void zero_u32_kernel(unsigned* p) { *p = 0u; }

// abs-max of W into *out (uint-ordered float bits; all values >= 0)
__global__ void wabsmax_kernel(const float* __restrict__ in, int n, unsigned* out) {
  float m = 0.f;
  for (int i = blockIdx.x * blockDim.x + threadIdx.x; i < n; i += gridDim.x * blockDim.x)
    m = fmaxf(m, fabsf(in[i]));
#pragma unroll
  for (int off = 32; off >= 1; off >>= 1)
    m = fmaxf(m, __shfl_xor(m, off));
  if ((threadIdx.x & 63) == 0) atomicMax(out, __float_as_uint(m));
}

// quantize W to i8 with scale s = wmax/127
__global__ void quant_w_kernel(const float* __restrict__ W, signed char* __restrict__ out,
                               const unsigned* __restrict__ wmax, int n) {
  float mx = __uint_as_float(*wmax);
  float inv = mx > 0.f ? 127.f / mx : 0.f;
  int i = (blockIdx.x * blockDim.x + threadIdx.x) * 4;
  if (i + 3 < n) {
    float4 v = *(const float4*)(W + i);
    int q0 = (int)__builtin_rintf(v.x * inv);
    int q1 = (int)__builtin_rintf(v.y * inv);
    int q2 = (int)__builtin_rintf(v.z * inv);
    int q3 = (int)__builtin_rintf(v.w * inv);
    unsigned p = (unsigned)(q0 & 255) | ((unsigned)(q1 & 255) << 8) |
                 ((unsigned)(q2 & 255) << 16) | ((unsigned)(q3 & 255) << 24);
    *(unsigned*)(out + i) = p;
  }
}

// ---------------- GEMM: C[M,N] = A[M,K] * B[N,K]^T + bias[N] ----------------

#define BM 128
#define BN 128
#define BKT 32
#define LDK 40  // padded leading dim (f16 elems) to dodge bank conflicts

template <bool A_IS_F32>
__global__ __launch_bounds__(256, 2) void gemm_f16_kernel(
    const void* __restrict__ Aptr,    // [M][K]
    const f16* __restrict__ B,        // [N][K]
    const float* __restrict__ bias,   // [N]
    float* __restrict__ C,            // [M][N]
    int M, int N, int K) {
  __shared__ f16 As[BM][LDK];
  __shared__ f16 Bs[BN][LDK];

  const int tid = threadIdx.x;
  const int bm = blockIdx.y, bn = blockIdx.x;
  const int wave = tid >> 6, lane = tid & 63;
  const int wm = wave >> 1, wn = wave & 1;

  f32x4 acc[4][4] = {};

  for (int k0 = 0; k0 < K; k0 += BKT) {
#pragma unroll
    for (int it = 0; it < 2; ++it) {
      int idx = tid + it * 256;          // 0..511
      int row = idx >> 2;                // 0..127
      int kc  = (idx & 3) << 3;          // 0,8,16,24
      if (A_IS_F32) {
        const float* Af = (const float*)Aptr + (size_t)(bm * BM + row) * K + k0 + kc;
        float4 v0 = *(const float4*)Af;
        float4 v1 = *(const float4*)(Af + 4);
        f16x8 h;
        h[0] = (f16)v0.x; h[1] = (f16)v0.y; h[2] = (f16)v0.z; h[3] = (f16)v0.w;
        h[4] = (f16)v1.x; h[5] = (f16)v1.y; h[6] = (f16)v1.z; h[7] = (f16)v1.w;
        *(f16x8*)&As[row][kc] = h;
      } else {
        const f16* Ah = (const f16*)Aptr + (size_t)(bm * BM + row) * K + k0 + kc;
        *(f16x8*)&As[row][kc] = *(const f16x8*)Ah;
      }
      const f16* Bh = B + (size_t)(bn * BN + row) * K + k0 + kc;
      *(f16x8*)&Bs[row][kc] = *(const f16x8*)Bh;
    }
    __syncthreads();

    const int fr = lane & 15;
    const int fk = (lane >> 4) << 3;  // 0,8,16,24
    f16x8 af[4], bf[4];
#pragma unroll
    for (int i = 0; i < 4; ++i) af[i] = *(const f16x8*)&As[wm * 64 + i * 16 + fr][fk];
#pragma unroll
    for (int j = 0; j < 4; ++j) bf[j] = *(const f16x8*)&Bs[wn * 64 + j * 16 + fr][fk];
#pragma unroll
    for (int i = 0; i < 4; ++i)
#pragma unroll
      for (int j = 0; j < 4; ++j)
        acc[i][j] = __builtin_amdgcn_mfma_f32_16x16x32_f16(af[i], bf[j], acc[i][j], 0, 0, 0);
    __syncthreads();
  }

  const int fr = lane & 15;
  const int fq = lane >> 4;
#pragma unroll
  for (int i = 0; i < 4; ++i)
#pragma unroll
    for (int j = 0; j < 4; ++j)
#pragma unroll
      for (int r = 0; r < 4; ++r) {
        int row = bm * BM + wm * 64 + i * 16 + fq * 4 + r;
        int col = bn * BN + wn * 64 + j * 16 + fr;
        C[(size_t)row * N + col] = acc[i][j][r] + bias[col];
      }
}

// ---------------- recurrent scan (int8, pressure-capped pipeline) ----------------
// One block (512 thr, 8 waves) per batch row; thread tid owns output tid.
// W row = 32 NAMED int4 values (128 dwords i8) -> SSA, no SROA threshold.
// Root cause of rounds 1-9 (W never register-resident): the 16-32 independent
// per-step ds_read_b128 h-loads got HOISTED en masse, peak pressure > budget,
// and the allocator spilled loop-invariant W. Fix: 2-deep software pipeline
// (hA/hB) with sched_barrier(0) fences -> at most ONE h-load in flight beyond
// the consumer; peak pressure ~ 128(W) + 8(h) + ~25 misc < 256-reg budget
// (amdgpu_waves_per_eu(2,2) = 2 waves/SIMD target).
// Pipe model w/ resident W: VALU ~640 cyc/SIMD, LDS ~935 cyc/CU -> ~1100 cyc.

#define RT 512

#define CH_A(W, cnext)                                        \
  { hB = bcp[cnext];                                          \
    a0 = sdot4(W.x, hA.x, a0); a1 = sdot4(W.y, hA.y, a1);     \
    a2 = sdot4(W.z, hA.z, a2); a3 = sdot4(W.w, hA.w, a3);     \
    __builtin_amdgcn_sched_barrier(0); }
#define CH_B(W, cnext)                                        \
  { hA = bcp[cnext];                                          \
    a0 = sdot4(W.x, hB.x, a0); a1 = sdot4(W.y, hB.y, a1);     \
    a2 = sdot4(W.z, hB.z, a2); a3 = sdot4(W.w, hB.w, a3);     \
    __builtin_amdgcn_sched_barrier(0); }

__global__ __attribute__((amdgpu_flat_work_group_size(RT, RT),
                          amdgpu_waves_per_eu(2, 2)))
void rnn_scan_kernel(
    const signed char* __restrict__ Whq,  // [512][512] i8
    const unsigned* __restrict__ wmax,    // scale source
    const float* __restrict__ h0,         // [B][512] f32
    const float* __restrict__ xp,         // [B][T][512] f32 (pre-act incl. biases)
    f16* __restrict__ hs,                 // [B][T][512] f16 (out, for y-GEMM)
    float* __restrict__ hn,               // [B][512] f32 (out)
    int T) {
  __shared__ __align__(16) signed char hbuf[2][RT];   // 1 KB
  const int tid = threadIdx.x;
  const int b   = blockIdx.x;

  // combined dequant scale: value = acc_int * (wmax/127) * (1/127)
  const float qs = __uint_as_float(*wmax) * (1.0f / 16129.0f);

  // W row tid: 128 dwords of packed i8 as 32 NAMED int4s
  const int4* wr = (const int4*)(Whq + (size_t)tid * 512);
  int4 W0 =wr[0],  W1 =wr[1],  W2 =wr[2],  W3 =wr[3],
       W4 =wr[4],  W5 =wr[5],  W6 =wr[6],  W7 =wr[7],
       W8 =wr[8],  W9 =wr[9],  W10=wr[10], W11=wr[11],
       W12=wr[12], W13=wr[13], W14=wr[14], W15=wr[15],
       W16=wr[16], W17=wr[17], W18=wr[18], W19=wr[19],
       W20=wr[20], W21=wr[21], W22=wr[22], W23=wr[23],
       W24=wr[24], W25=wr[25], W26=wr[26], W27=wr[27],
       W28=wr[28], W29=wr[29], W30=wr[30], W31=wr[31];

  {
    float hv = h0[(size_t)b * 512 + tid];
    hv = fminf(1.f, fmaxf(-1.f, hv));
    hbuf[0][tid] = (signed char)(int)__builtin_rintf(127.f * hv);
  }
  __syncthreads();

  const float* xpb = xp + (size_t)b * T * 512 + tid;
  f16* hsb = hs + (size_t)b * T * 512 + tid;

  int cur = 0;
  float hlast = 0.f;
  float xv = xpb[0];
  for (int t = 0; t < T; ++t) {
    int tn = t + 1 < T ? t + 1 : t;
    float xn = xpb[(size_t)tn * 512];   // prefetch next step's xp

    const int4* bcp = (const int4*)hbuf[cur];
    int a0 = 0, a1 = 0, a2 = 0, a3 = 0;
    int4 hA = bcp[0], hB;
    __builtin_amdgcn_sched_barrier(0);
    CH_A(W0 , 1)  CH_B(W1 , 2)  CH_A(W2 , 3)  CH_B(W3 , 4)
    CH_A(W4 , 5)  CH_B(W5 , 6)  CH_A(W6 , 7)  CH_B(W7 , 8)
    CH_A(W8 , 9)  CH_B(W9 ,10)  CH_A(W10,11)  CH_B(W11,12)
    CH_A(W12,13)  CH_B(W13,14)  CH_A(W14,15)  CH_B(W15,16)
    CH_A(W16,17)  CH_B(W17,18)  CH_A(W18,19)  CH_B(W19,20)
    CH_A(W20,21)  CH_B(W21,22)  CH_A(W22,23)  CH_B(W23,24)
    CH_A(W24,25)  CH_B(W25,26)  CH_A(W26,27)  CH_B(W27,28)
    CH_A(W28,29)  CH_B(W29,30)  CH_A(W30,31)
    // last chunk (31) uses hB, no prefetch
    a0 = sdot4(W31.x, hB.x, a0); a1 = sdot4(W31.y, hB.y, a1);
    a2 = sdot4(W31.z, hB.z, a2); a3 = sdot4(W31.w, hB.w, a3);

    float acc = (float)((a0 + a1) + (a2 + a3)) * qs + xv;
    // tanh(x) = 1 - 2/(exp(2x)+1); branch-free
    float e = __expf(2.0f * acc);
    float hnew = 1.0f - 2.0f * __builtin_amdgcn_rcpf(e + 1.0f);
    hlast = hnew;
    hsb[(size_t)t * 512] = (f16)hnew;
    hbuf[cur ^ 1][tid] = (signed char)(int)__builtin_rintf(127.f * hnew);
    __syncthreads();
    cur ^= 1;
    xv = xn;
  }
  hn[(size_t)b * 512 + tid] = hlast;
}

// ---------------- launch ----------------

extern "C" void kernel_launch(void* const* d_in, const int* in_sizes, int n_in,
                              void* d_out, int out_size, void* d_ws, size_t ws_size,
                              hipStream_t stream) {
  const float* x    = (const float*)d_in[0];
  const float* h0   = (const float*)d_in[1];
  const float* W_xh = (const float*)d_in[2];
  const float* b_xh = (const float*)d_in[3];
  const float* W_hh = (const float*)d_in[4];
  const float* b_hh = (const float*)d_in[5];
  const float* W_hy = (const float*)d_in[6];
  const float* b_hy = (const float*)d_in[7];

  const int H = 512;
  const int B = in_sizes[1] / H;            // 64
  const int T = in_sizes[0] / (B * H);      // 1024
  const int M = B * T;                      // 65536

  float* out = (float*)d_out;               // y [M][512] then h_n [B][512]
  float* xpb = out;                         // reuse y region as xp scratch
  float* hn  = out + (size_t)M * H;

  char* w = (char*)d_ws;
  f16*         hsb    = (f16*)w;                              // M*H*2 bytes
  f16*         Wxh_h  = (f16*)(w + (size_t)M * H * 2);        // H*H f16
  f16*         Why_h  = Wxh_h + H * H;                        // H*H f16
  signed char* Whq    = (signed char*)(Why_h + H * H);        // H*H i8
  float*       biasc  = (float*)(Whq + H * H);                // H f32
  unsigned*    wmax   = (unsigned*)(biasc + H);               // 1 u32

  const int WN = H * H;  // 262144
  cvt_f32_to_f16<<<WN / 1024, 256, 0, stream>>>(W_xh, Wxh_h, WN);
  cvt_f32_to_f16<<<WN / 1024, 256, 0, stream>>>(W_hy, Why_h, WN);
  bias_comb_kernel<<<2, 256, 0, stream>>>(b_xh, b_hh, biasc, H);

  // quantize W_hh to i8 with measured absmax scale
  zero_u32_kernel<<<1, 1, 0, stream>>>(wmax);
  wabsmax_kernel<<<64, 256, 0, stream>>>(W_hh, WN, wmax);
  quant_w_kernel<<<WN / 1024, 256, 0, stream>>>(W_hh, Whq, wmax, WN);

  // xp = x @ W_xh^T + (b_xh + b_hh)   (written into d_out)
  gemm_f16_kernel<true><<<dim3(H / BN, M / BM), 256, 0, stream>>>(
      x, Wxh_h, biasc, xpb, M, H, H);

  // sequential scan; writes hs (f16, ws) and h_n (f32, d_out tail)
  rnn_scan_kernel<<<B, RT, 0, stream>>>(Whq, wmax, h0, xpb, hsb, hn, T);

  // y = hs @ W_hy^T + b_hy   (overwrites xp region of d_out)
  gemm_f16_kernel<false><<<dim3(H / BN, M / BM), 256, 0, stream>>>(
      hsb, Why_h, b_hy, out, M, H, H);
}